// Round 23
// baseline (14904.671 us; speedup 1.0000x reference)
//
#include <hip/hip_runtime.h>
#include <math.h>

// NCA: B=8, H=W=256, C=16, 16 steps.
// R22 post-mortem: hbuf_lo placed 576 FLOATS (=2304B) after hbuf_hi, but
// hbuf_hi needs 4608B (64x36 ushorts) -> waves 2/3's h overlapped hbuf_lo ->
// absmax 1.54. ushort-count vs float-count confusion.
// R23 = R22 with hbuf_lo at smem+1152 (one-line fix). Design unchanged:
// B-frags from global W0hiT/loT (L1/L2-hot), zero loop barriers, LDS 51.7KB
// -> 3 blocks/CU, hbuf wave-local in dead xs region.

#define HW 256
#define NPIX (8*HW*HW)   // 524288

typedef __attribute__((ext_vector_type(8))) short short8;
typedef __attribute__((ext_vector_type(4))) float f32x4;

__device__ __forceinline__ float4 f4max(float4 a, float4 b) {
    return make_float4(fmaxf(a.x,b.x), fmaxf(a.y,b.y), fmaxf(a.z,b.z), fmaxf(a.w,b.w));
}
__device__ __forceinline__ unsigned short bf16_rne(float v) {
    unsigned int u = __float_as_uint(v);
    unsigned int r = u + 0x7FFFu + ((u >> 16) & 1u);
    return (unsigned short)(r >> 16);
}
__device__ __forceinline__ float bf16f(unsigned short h) {
    return __uint_as_float(((unsigned int)h) << 16);
}

// Sobel bank + W0 split/transpose [j][k] + W1 split/transpose [ch][j].
__global__ void init_kernel(const float* __restrict__ W0,
                            const float* __restrict__ W1,
                            float* __restrict__ filt,
                            unsigned short* __restrict__ W0hiT,
                            unsigned short* __restrict__ W0loT,
                            unsigned short* __restrict__ W1hiT2,
                            unsigned short* __restrict__ W1loT2) {
    int t = blockIdx.x * blockDim.x + threadIdx.x;
    int nth = gridDim.x * blockDim.x;
    for (int idx = t; idx < 32768; idx += nth) {
        int j = idx >> 7, k = idx & 127;
        float v = W0[k * 256 + j];
        unsigned short hi = bf16_rne(v);
        unsigned short lo = bf16_rne(v - bf16f(hi));
        W0hiT[idx] = hi;
        W0loT[idx] = lo;
    }
    for (int idx = t; idx < 4096; idx += nth) {
        int ch = idx >> 8, j = idx & 255;
        float v = W1[j * 16 + ch];
        unsigned short hi = bf16_rne(v);
        unsigned short lo = bf16_rne(v - bf16f(hi));
        W1hiT2[idx] = hi;
        W1loT2[idx] = lo;
    }
    if (t < 6) {
        int f = t;
        int size = 3 + 2*(f >> 1);
        int p0 = (7 - size) >> 1;
        int isY = f & 1;
        float vals[49];
        float norm = 0.f;
        for (int a = 0; a < 7; a++) {
            for (int b = 0; b < 7; b++) {
                float v = 0.f;
                if (a >= p0 && a < p0+size && b >= p0 && b < p0+size) {
                    float fy = (float)(a - 3), fx = (float)(b - 3);
                    float den = fx*fx + fy*fy;
                    if (den == 0.f) den = 1.f;
                    v = (isY ? fy : fx) / den;
                }
                vals[a*7+b] = v;
                norm += fabsf(v);
            }
        }
        float inv = 1.f / norm;
        for (int i = 0; i < 49; i++) filt[f*49 + i] = vals[i] * inv;
    }
}

__launch_bounds__(256, 2)
__global__ void step_main(const float* __restrict__ x,
                          float* __restrict__ xmid,
                          const unsigned char* __restrict__ prelife_in,
                          unsigned char* __restrict__ prelife_out,
                          const float* __restrict__ filt_g,
                          const unsigned short* __restrict__ W0hiT,
                          const unsigned short* __restrict__ W0loT,
                          const unsigned short* __restrict__ W1hiT2,
                          const unsigned short* __restrict__ W1loT2,
                          const float* __restrict__ b0,
                          const float* __restrict__ stoch_s,
                          const float* __restrict__ valid,
                          int apply_mask) {
    // floats: [0,4214) xs 3920 + filt [3920,4214) (phase1)
    //         ALIAS phase2: hbuf_hi [0,1152) + hbuf_lo [1152,2304) (<3920 OK)
    //         [4224,8576) perc_hi us[64][136]  [8576,12928) perc_lo
    // total 12928 fl = 51712 B -> 3 blocks/CU
    __shared__ float smem[12928];
    float*          xs      = smem;
    float*          filt_s  = smem + 3920;
    unsigned short* hbuf_hi = (unsigned short*)smem;            // phase 2
    unsigned short* hbuf_lo = (unsigned short*)(smem + 1152);   // phase 2
    unsigned short* perc_hi = (unsigned short*)(smem + 4224);
    unsigned short* perc_lo = (unsigned short*)(smem + 8576);

    const int t   = threadIdx.x;
    const int b   = blockIdx.z;
    const int ty0 = blockIdx.y * 8;
    const int tx0 = blockIdx.x * 8;

    for (int i = t; i < 294; i += 256) filt_s[i] = filt_g[i];

    // stage x tile + halo with FUSED life-mask
    if (t < 196) {
        const int ly = t / 14, lx = t - ly*14;
        const int gy = ty0 + ly - 3, gx = tx0 + lx - 3;
        const bool inb = ((unsigned)gy < 256u) && ((unsigned)gx < 256u);
        float4 v0 = make_float4(0.f,0.f,0.f,0.f), v1 = v0, v2 = v0, v3 = v0;
        if (inb) {
            const int pix = (b << 16) + (gy << 8) + gx;
            const float* srcp = &x[(size_t)pix << 4];
            v0 = *(const float4*)(srcp);
            v1 = *(const float4*)(srcp + 4);
            v2 = *(const float4*)(srcp + 8);
            v3 = *(const float4*)(srcp + 12);
            if (apply_mask) {
                float m = -INFINITY;
                #pragma unroll
                for (int dy = -1; dy <= 1; dy++) {
                    #pragma unroll
                    for (int dxo = -1; dxo <= 1; dxo++) {
                        int yy = gy + dy, xx2 = gx + dxo;
                        if ((unsigned)yy < 256u && (unsigned)xx2 < 256u)
                            m = fmaxf(m, x[((size_t)((b<<16)+(yy<<8)+xx2) << 4) + 3]);
                    }
                }
                float s = (prelife_in[pix] != 0 && m > 0.1f) ? valid[pix] : 0.f;
                v0.x *= s; v0.y *= s; v0.z *= s; v0.w *= s;
                v1.x *= s; v1.y *= s; v1.z *= s; v1.w *= s;
                v2.x *= s; v2.y *= s; v2.z *= s; v2.w *= s;
                v3.x *= s; v3.y *= s; v3.z *= s; v3.w *= s;
            }
        }
        float* dstp = &xs[t * 20];
        *(float4*)(dstp)      = v0;
        *(float4*)(dstp + 4)  = v1;
        *(float4*)(dstp + 8)  = v2;
        *(float4*)(dstp + 12) = v3;
    }
    __syncthreads();

    {   // ---- phase 1: sparse conv + pools -> perc (bf16 hi/lo) ----
        const int p  = t & 63;
        const int q  = t >> 6;
        const int py = p >> 3, px1 = p & 7;
        const int gy = ty0 + py, gx = tx0 + px1;
        const int q4 = q << 2;

        float4 y4[6];
        #pragma unroll
        for (int f = 0; f < 6; f++) y4[f] = make_float4(0.f,0.f,0.f,0.f);

        #pragma unroll
        for (int a = 0; a < 7; a++) {
            #pragma unroll
            for (int bb = 0; bb < 7; bb++) {
                float4 xv = *(const float4*)&xs[((py+a)*14 + (px1+bb))*20 + q4];
                {   // f=4,5: full 7x7
                    float w4 = filt_s[4*49 + a*7 + bb];
                    float w5 = filt_s[5*49 + a*7 + bb];
                    y4[4].x = fmaf(w4, xv.x, y4[4].x); y4[4].y = fmaf(w4, xv.y, y4[4].y);
                    y4[4].z = fmaf(w4, xv.z, y4[4].z); y4[4].w = fmaf(w4, xv.w, y4[4].w);
                    y4[5].x = fmaf(w5, xv.x, y4[5].x); y4[5].y = fmaf(w5, xv.y, y4[5].y);
                    y4[5].z = fmaf(w5, xv.z, y4[5].z); y4[5].w = fmaf(w5, xv.w, y4[5].w);
                }
                if (a >= 1 && a <= 5 && bb >= 1 && bb <= 5) {   // f=2,3: 5x5
                    float w2 = filt_s[2*49 + a*7 + bb];
                    float w3 = filt_s[3*49 + a*7 + bb];
                    y4[2].x = fmaf(w2, xv.x, y4[2].x); y4[2].y = fmaf(w2, xv.y, y4[2].y);
                    y4[2].z = fmaf(w2, xv.z, y4[2].z); y4[2].w = fmaf(w2, xv.w, y4[2].w);
                    y4[3].x = fmaf(w3, xv.x, y4[3].x); y4[3].y = fmaf(w3, xv.y, y4[3].y);
                    y4[3].z = fmaf(w3, xv.z, y4[3].z); y4[3].w = fmaf(w3, xv.w, y4[3].w);
                }
                if (a >= 2 && a <= 4 && bb >= 2 && bb <= 4) {   // f=0,1: 3x3
                    float w0 = filt_s[0*49 + a*7 + bb];
                    float w1 = filt_s[1*49 + a*7 + bb];
                    y4[0].x = fmaf(w0, xv.x, y4[0].x); y4[0].y = fmaf(w0, xv.y, y4[0].y);
                    y4[0].z = fmaf(w0, xv.z, y4[0].z); y4[0].w = fmaf(w0, xv.w, y4[0].w);
                    y4[1].x = fmaf(w1, xv.x, y4[1].x); y4[1].y = fmaf(w1, xv.y, y4[1].y);
                    y4[1].z = fmaf(w1, xv.z, y4[1].z); y4[1].w = fmaf(w1, xv.w, y4[1].w);
                }
            }
        }
        float4 m5 = make_float4(-INFINITY,-INFINITY,-INFINITY,-INFINITY);
        #pragma unroll
        for (int dy = -2; dy <= 2; dy++) {
            #pragma unroll
            for (int dx2 = -2; dx2 <= 2; dx2++) {
                if ((unsigned)(gy+dy) < 256u && (unsigned)(gx+dx2) < 256u)
                    m5 = f4max(m5, *(const float4*)&xs[((py+3+dy)*14 + (px1+3+dx2))*20 + q4]);
            }
        }
        float4 xc = *(const float4*)&xs[((py+3)*14 + (px1+3))*20 + q4];

        #define SPLIT4(arridx, v) { \
            unsigned short h0 = bf16_rne((v).x), h1 = bf16_rne((v).y); \
            unsigned short h2 = bf16_rne((v).z), h3 = bf16_rne((v).w); \
            unsigned short l0 = bf16_rne((v).x - bf16f(h0)); \
            unsigned short l1 = bf16_rne((v).y - bf16f(h1)); \
            unsigned short l2 = bf16_rne((v).z - bf16f(h2)); \
            unsigned short l3 = bf16_rne((v).w - bf16f(h3)); \
            *(ushort4*)&perc_hi[arridx] = make_ushort4(h0,h1,h2,h3); \
            *(ushort4*)&perc_lo[arridx] = make_ushort4(l0,l1,l2,l3); }

        const int prow = p * 136;
        SPLIT4(prow +       q4, xc);
        SPLIT4(prow + 16  + q4, y4[0]);
        SPLIT4(prow + 32  + q4, y4[1]);
        SPLIT4(prow + 48  + q4, y4[2]);
        SPLIT4(prow + 64  + q4, y4[3]);
        SPLIT4(prow + 80  + q4, y4[4]);
        SPLIT4(prow + 96  + q4, y4[5]);
        SPLIT4(prow + 112 + q4, m5);
        #undef SPLIT4

        if (q == 0) {
            float pre = -INFINITY;
            #pragma unroll
            for (int dy = -1; dy <= 1; dy++) {
                #pragma unroll
                for (int dx2 = -1; dx2 <= 1; dx2++) {
                    if ((unsigned)(gy+dy) < 256u && (unsigned)(gx+dx2) < 256u)
                        pre = fmaxf(pre, xs[((py+3+dy)*14 + (px1+3+dx2))*20 + 3]);
                }
            }
            prelife_out[(b << 16) + (gy << 8) + gx] = (pre > 0.1f) ? 1 : 0;
        }
    }
    __syncthreads();   // xs reads done; perc published. xs region -> hbuf.

    // ---- phase 2: GEMM1 + GEMM2 both MFMA, weights from global ----
    const int lane = t & 63;
    const int wid  = t >> 6;        // m-tile (16 px)
    const int l15  = lane & 15;
    const int l4   = lane >> 4;
    const int aoff  = (wid*16 + l15)*136 + 8*l4;  // GEMM1 A base (+32*ks)
    const int bb0   = l15*128 + 8*l4;             // W0T frag base, n-tile 0
    const int bb1   = (16 + l15)*128 + 8*l4;      // n-tile 1  (+jc*4096+ks*32)
    const int hwr   = (wid*16 + 4*l4)*36 + l15;   // hbuf write base (+r*36)
    const int hrd   = (wid*16 + l15)*36 + 8*l4;   // hbuf A-frag base
    const int w1off = l15*256 + 8*l4;             // W1T2 frag base (+jc*32)

    // hoist GEMM1 A-frags (loop-invariant)
    short8 ah0 = *(const short8*)&perc_hi[aoff +  0];
    short8 ah1 = *(const short8*)&perc_hi[aoff + 32];
    short8 ah2 = *(const short8*)&perc_hi[aoff + 64];
    short8 ah3 = *(const short8*)&perc_hi[aoff + 96];
    short8 al0 = *(const short8*)&perc_lo[aoff +  0];
    short8 al1 = *(const short8*)&perc_lo[aoff + 32];
    short8 al2 = *(const short8*)&perc_lo[aoff + 64];
    short8 al3 = *(const short8*)&perc_lo[aoff + 96];

    f32x4 dacc = {0.f, 0.f, 0.f, 0.f};   // dx accumulator (C: col=ch, row=px)

    #pragma unroll 1
    for (int jc = 0; jc < 8; jc++) {
        const int cb = jc << 12;   // jc*32 rows * 128

        f32x4 acc0 = {0.f, 0.f, 0.f, 0.f};
        f32x4 acc1 = {0.f, 0.f, 0.f, 0.f};

        #define KSTEP(accv, bb, AH, AL, ks) { \
            short8 bh = *(const short8*)&W0hiT[cb + (bb) + (ks)*32]; \
            short8 bl = *(const short8*)&W0loT[cb + (bb) + (ks)*32]; \
            accv = __builtin_amdgcn_mfma_f32_16x16x32_bf16(AL, bh, accv, 0, 0, 0); \
            accv = __builtin_amdgcn_mfma_f32_16x16x32_bf16(AH, bl, accv, 0, 0, 0); \
            accv = __builtin_amdgcn_mfma_f32_16x16x32_bf16(AH, bh, accv, 0, 0, 0); }

        KSTEP(acc0, bb0, ah0, al0, 0)
        KSTEP(acc0, bb0, ah1, al1, 1)
        KSTEP(acc0, bb0, ah2, al2, 2)
        KSTEP(acc0, bb0, ah3, al3, 3)
        KSTEP(acc1, bb1, ah0, al0, 0)
        KSTEP(acc1, bb1, ah1, al1, 1)
        KSTEP(acc1, bb1, ah2, al2, 2)
        KSTEP(acc1, bb1, ah3, al3, 3)
        #undef KSTEP

        // bias+relu, split h -> hbuf (WAVE-LOCAL: no barrier needed)
        {
            float bias0 = b0[jc*32 + l15];
            float bias1 = b0[jc*32 + 16 + l15];
            #pragma unroll
            for (int r = 0; r < 4; r++) {
                float h0 = fmaxf(acc0[r] + bias0, 0.f);
                float h1 = fmaxf(acc1[r] + bias1, 0.f);
                unsigned short hh0 = bf16_rne(h0);
                unsigned short hl0 = bf16_rne(h0 - bf16f(hh0));
                unsigned short hh1 = bf16_rne(h1);
                unsigned short hl1 = bf16_rne(h1 - bf16f(hh1));
                hbuf_hi[hwr + r*36]      = hh0;
                hbuf_lo[hwr + r*36]      = hl0;
                hbuf_hi[hwr + r*36 + 16] = hh1;
                hbuf_lo[hwr + r*36 + 16] = hl1;
            }
        }

        // GEMM2: dacc += h(px x 32j) * W1T2(32j x 16ch), 3 MFMAs
        {
            short8 hhf = *(const short8*)&hbuf_hi[hrd];
            short8 hlf = *(const short8*)&hbuf_lo[hrd];
            short8 w1h = *(const short8*)&W1hiT2[w1off + jc*32];
            short8 w1l = *(const short8*)&W1loT2[w1off + jc*32];
            dacc = __builtin_amdgcn_mfma_f32_16x16x32_bf16(hlf, w1h, dacc, 0, 0, 0);
            dacc = __builtin_amdgcn_mfma_f32_16x16x32_bf16(hhf, w1l, dacc, 0, 0, 0);
            dacc = __builtin_amdgcn_mfma_f32_16x16x32_bf16(hhf, w1h, dacc, 0, 0, 0);
        }
    }

    // ---- epilogue: lane = (ch=l15, px=16*wid+4*l4+r) ----
    const int pxb = wid*16 + 4*l4;
    #pragma unroll
    for (int r = 0; r < 4; r++) {
        const int px   = pxb + r;
        const int pix2 = (b << 16) + ((ty0 + (px >> 3)) << 8) + (tx0 + (px & 7));
        float fire = (stoch_s[pix2] > 0.5f) ? 1.f : 0.f;
        float xc = bf16f(perc_hi[px*136 + l15]) + bf16f(perc_lo[px*136 + l15]);
        xmid[((size_t)pix2 << 4) + l15] = fmaf(fire, dacc[r], xc);
    }
}

// Final life masking (after step 16): alpha read from xbuf channel 3.
__global__ void step_mask(float* __restrict__ xbuf,
                          const unsigned char* __restrict__ prelife,
                          const float* __restrict__ valid) {
    int pix = blockIdx.x * 256 + threadIdx.x;
    int b = pix >> 16;
    int y = (pix >> 8) & 255;
    int x = pix & 255;
    float m = -INFINITY;
    #pragma unroll
    for (int dy = -1; dy <= 1; dy++) {
        #pragma unroll
        for (int dxo = -1; dxo <= 1; dxo++) {
            int yy = y + dy, xx = x + dxo;
            if ((unsigned)yy < 256u && (unsigned)xx < 256u)
                m = fmaxf(m, xbuf[((size_t)((b << 16) + (yy << 8) + xx) << 4) + 3]);
        }
    }
    float s = (prelife[pix] != 0 && m > 0.1f) ? valid[pix] : 0.f;
    float4* xp = (float4*)&xbuf[(size_t)pix << 4];
    #pragma unroll
    for (int i = 0; i < 4; i++) {
        float4 v = xp[i];
        v.x *= s; v.y *= s; v.z *= s; v.w *= s;
        xp[i] = v;
    }
}

extern "C" void kernel_launch(void* const* d_in, const int* in_sizes, int n_in,
                              void* d_out, int out_size, void* d_ws, size_t ws_size,
                              hipStream_t stream) {
    const float* x0    = (const float*)d_in[0];
    const float* valid = (const float*)d_in[1];
    const float* stoch = (const float*)d_in[2];
    const float* W0    = (const float*)d_in[3];
    const float* b0    = (const float*)d_in[4];
    const float* W1    = (const float*)d_in[5];

    float* ws   = (float*)d_ws;
    float* xA   = ws;                                    // [0, 8388608)
    unsigned char* plA = (unsigned char*)(ws + 8388608); // 512KB
    unsigned char* plB = plA + 524288;                   // 512KB
    float* filt = ws + 8650752;                          // 320 fl
    unsigned short* W0hiT  = (unsigned short*)(ws + 8651072);  // 32768 us
    unsigned short* W0loT  = (unsigned short*)(ws + 8667456);  // 32768 us
    unsigned short* W1hiT2 = (unsigned short*)(ws + 8683840);  // 4096 us
    unsigned short* W1loT2 = (unsigned short*)(ws + 8685888);  // 4096 us
    float* out  = (float*)d_out;

    init_kernel<<<128, 256, 0, stream>>>(W0, W1, filt, W0hiT, W0loT,
                                         W1hiT2, W1loT2);

    const float* src = x0;
    for (int k = 1; k <= 16; k++) {
        float* dst = (k & 1) ? xA : out;          // step 16 lands in d_out
        unsigned char* wr = (k & 1) ? plB : plA;
        unsigned char* rd = (k & 1) ? plA : plB;
        step_main<<<dim3(32,32,8), 256, 0, stream>>>(
            src, dst, rd, wr, filt, W0hiT, W0loT, W1hiT2, W1loT2, b0,
            stoch + (size_t)(k-1)*NPIX, valid, (k > 1) ? 1 : 0);
        src = dst;
    }
    step_mask<<<NPIX/256, 256, 0, stream>>>(out, plA, valid);
}

// Round 24
// 10597.757 us; speedup vs baseline: 1.4064x; 1.4064x over previous
//
#include <hip/hip_runtime.h>
#include <math.h>

// NCA: B=8, H=W=256, C=16, 16 steps.
// R24 = R21 verbatim (measured best: 10.59ms wall, step ~708us, absmax
// 0.015625). R23 taught: (a) usable LDS pool ~153.6KB (3 blocks needs
// <=51.2KB - unreachable with perc hi/lo + w0 staging); (b) global B-frags
// slower than LDS dbuf (+37%: 256B-strided 16B/lane = 64 cache lines/instr,
// L1 latency exposed at 2 waves/SIMD). Reverting to the known-good design:
// both GEMMs MFMA (split-bf16), w0 LDS dbuf 1 barrier/chunk, hbuf wave-local.

#define HW 256
#define NPIX (8*HW*HW)   // 524288

typedef __attribute__((ext_vector_type(8))) short short8;
typedef __attribute__((ext_vector_type(4))) float f32x4;

__device__ __forceinline__ float4 f4max(float4 a, float4 b) {
    return make_float4(fmaxf(a.x,b.x), fmaxf(a.y,b.y), fmaxf(a.z,b.z), fmaxf(a.w,b.w));
}
__device__ __forceinline__ unsigned short bf16_rne(float v) {
    unsigned int u = __float_as_uint(v);
    unsigned int r = u + 0x7FFFu + ((u >> 16) & 1u);
    return (unsigned short)(r >> 16);
}
__device__ __forceinline__ float bf16f(unsigned short h) {
    return __uint_as_float(((unsigned int)h) << 16);
}

// Sobel bank + W0 split/transpose [j][k] + W1 split/transpose [ch][j].
__global__ void init_kernel(const float* __restrict__ W0,
                            const float* __restrict__ W1,
                            float* __restrict__ filt,
                            unsigned short* __restrict__ W0hiT,
                            unsigned short* __restrict__ W0loT,
                            unsigned short* __restrict__ W1hiT2,
                            unsigned short* __restrict__ W1loT2) {
    int t = blockIdx.x * blockDim.x + threadIdx.x;
    int nth = gridDim.x * blockDim.x;
    for (int idx = t; idx < 32768; idx += nth) {
        int j = idx >> 7, k = idx & 127;
        float v = W0[k * 256 + j];
        unsigned short hi = bf16_rne(v);
        unsigned short lo = bf16_rne(v - bf16f(hi));
        W0hiT[idx] = hi;
        W0loT[idx] = lo;
    }
    for (int idx = t; idx < 4096; idx += nth) {
        int ch = idx >> 8, j = idx & 255;
        float v = W1[j * 16 + ch];
        unsigned short hi = bf16_rne(v);
        unsigned short lo = bf16_rne(v - bf16f(hi));
        W1hiT2[idx] = hi;
        W1loT2[idx] = lo;
    }
    if (t < 6) {
        int f = t;
        int size = 3 + 2*(f >> 1);
        int p0 = (7 - size) >> 1;
        int isY = f & 1;
        float vals[49];
        float norm = 0.f;
        for (int a = 0; a < 7; a++) {
            for (int b = 0; b < 7; b++) {
                float v = 0.f;
                if (a >= p0 && a < p0+size && b >= p0 && b < p0+size) {
                    float fy = (float)(a - 3), fx = (float)(b - 3);
                    float den = fx*fx + fy*fy;
                    if (den == 0.f) den = 1.f;
                    v = (isY ? fy : fx) / den;
                }
                vals[a*7+b] = v;
                norm += fabsf(v);
            }
        }
        float inv = 1.f / norm;
        for (int i = 0; i < 49; i++) filt[f*49 + i] = vals[i] * inv;
    }
}

__launch_bounds__(256, 2)
__global__ void step_main(const float* __restrict__ x,
                          float* __restrict__ xmid,
                          const unsigned char* __restrict__ prelife_in,
                          unsigned char* __restrict__ prelife_out,
                          const float* __restrict__ filt_g,
                          const unsigned short* __restrict__ W0hiT,
                          const unsigned short* __restrict__ W0loT,
                          const unsigned short* __restrict__ W1hiT2,
                          const unsigned short* __restrict__ W1loT2,
                          const float* __restrict__ b0,
                          const float* __restrict__ stoch_s,
                          const float* __restrict__ valid,
                          int apply_mask) {
    // floats: [0,8704) w0 dbuf (hA|lA|hB|lB, 2176 fl each) ALIAS phase1
    //         xs[0,3920)+filt[3920,4214)
    //         [8704,13056) perc_hi us[64][136]  [13056,17408) perc_lo
    //         [17408,18560) hbuf_hi us[64][36]  [18560,19712) hbuf_lo
    __shared__ float smem[19712];
    float*          xs      = smem;
    float*          filt_s  = smem + 3920;
    unsigned short* w0hA    = (unsigned short*)smem;
    unsigned short* w0lA    = (unsigned short*)(smem + 2176);
    unsigned short* w0hB    = (unsigned short*)(smem + 4352);
    unsigned short* w0lB    = (unsigned short*)(smem + 6528);
    unsigned short* perc_hi = (unsigned short*)(smem + 8704);
    unsigned short* perc_lo = (unsigned short*)(smem + 13056);
    unsigned short* hbuf_hi = (unsigned short*)(smem + 17408);
    unsigned short* hbuf_lo = (unsigned short*)(smem + 18560);

    const int t   = threadIdx.x;
    const int b   = blockIdx.z;
    const int ty0 = blockIdx.y * 8;
    const int tx0 = blockIdx.x * 8;

    // staging geometry (chunk = 32j x 128k): row j'=t>>3, 16 k at (t&7)*16
    const int sgbase = ((t >> 3) << 7) + ((t & 7) << 4);
    const int swds   = (t >> 3) * 136 + ((t & 7) << 4);
    uint4 sh0 = *(const uint4*)&W0hiT[sgbase];
    uint4 sh1 = *(const uint4*)&W0hiT[sgbase + 8];
    uint4 sl0 = *(const uint4*)&W0loT[sgbase];
    uint4 sl1 = *(const uint4*)&W0loT[sgbase + 8];

    for (int i = t; i < 294; i += 256) filt_s[i] = filt_g[i];

    // stage x tile + halo with FUSED life-mask
    if (t < 196) {
        const int ly = t / 14, lx = t - ly*14;
        const int gy = ty0 + ly - 3, gx = tx0 + lx - 3;
        const bool inb = ((unsigned)gy < 256u) && ((unsigned)gx < 256u);
        float4 v0 = make_float4(0.f,0.f,0.f,0.f), v1 = v0, v2 = v0, v3 = v0;
        if (inb) {
            const int pix = (b << 16) + (gy << 8) + gx;
            const float* srcp = &x[(size_t)pix << 4];
            v0 = *(const float4*)(srcp);
            v1 = *(const float4*)(srcp + 4);
            v2 = *(const float4*)(srcp + 8);
            v3 = *(const float4*)(srcp + 12);
            if (apply_mask) {
                float m = -INFINITY;
                #pragma unroll
                for (int dy = -1; dy <= 1; dy++) {
                    #pragma unroll
                    for (int dxo = -1; dxo <= 1; dxo++) {
                        int yy = gy + dy, xx2 = gx + dxo;
                        if ((unsigned)yy < 256u && (unsigned)xx2 < 256u)
                            m = fmaxf(m, x[((size_t)((b<<16)+(yy<<8)+xx2) << 4) + 3]);
                    }
                }
                float s = (prelife_in[pix] != 0 && m > 0.1f) ? valid[pix] : 0.f;
                v0.x *= s; v0.y *= s; v0.z *= s; v0.w *= s;
                v1.x *= s; v1.y *= s; v1.z *= s; v1.w *= s;
                v2.x *= s; v2.y *= s; v2.z *= s; v2.w *= s;
                v3.x *= s; v3.y *= s; v3.z *= s; v3.w *= s;
            }
        }
        float* dstp = &xs[t * 20];
        *(float4*)(dstp)      = v0;
        *(float4*)(dstp + 4)  = v1;
        *(float4*)(dstp + 8)  = v2;
        *(float4*)(dstp + 12) = v3;
    }
    __syncthreads();

    {   // ---- phase 1: sparse conv + pools -> perc (bf16 hi/lo) ----
        const int p  = t & 63;
        const int q  = t >> 6;
        const int py = p >> 3, px1 = p & 7;
        const int gy = ty0 + py, gx = tx0 + px1;
        const int q4 = q << 2;

        float4 y4[6];
        #pragma unroll
        for (int f = 0; f < 6; f++) y4[f] = make_float4(0.f,0.f,0.f,0.f);

        #pragma unroll
        for (int a = 0; a < 7; a++) {
            #pragma unroll
            for (int bb = 0; bb < 7; bb++) {
                float4 xv = *(const float4*)&xs[((py+a)*14 + (px1+bb))*20 + q4];
                {   // f=4,5: full 7x7
                    float w4 = filt_s[4*49 + a*7 + bb];
                    float w5 = filt_s[5*49 + a*7 + bb];
                    y4[4].x = fmaf(w4, xv.x, y4[4].x); y4[4].y = fmaf(w4, xv.y, y4[4].y);
                    y4[4].z = fmaf(w4, xv.z, y4[4].z); y4[4].w = fmaf(w4, xv.w, y4[4].w);
                    y4[5].x = fmaf(w5, xv.x, y4[5].x); y4[5].y = fmaf(w5, xv.y, y4[5].y);
                    y4[5].z = fmaf(w5, xv.z, y4[5].z); y4[5].w = fmaf(w5, xv.w, y4[5].w);
                }
                if (a >= 1 && a <= 5 && bb >= 1 && bb <= 5) {   // f=2,3: 5x5
                    float w2 = filt_s[2*49 + a*7 + bb];
                    float w3 = filt_s[3*49 + a*7 + bb];
                    y4[2].x = fmaf(w2, xv.x, y4[2].x); y4[2].y = fmaf(w2, xv.y, y4[2].y);
                    y4[2].z = fmaf(w2, xv.z, y4[2].z); y4[2].w = fmaf(w2, xv.w, y4[2].w);
                    y4[3].x = fmaf(w3, xv.x, y4[3].x); y4[3].y = fmaf(w3, xv.y, y4[3].y);
                    y4[3].z = fmaf(w3, xv.z, y4[3].z); y4[3].w = fmaf(w3, xv.w, y4[3].w);
                }
                if (a >= 2 && a <= 4 && bb >= 2 && bb <= 4) {   // f=0,1: 3x3
                    float w0 = filt_s[0*49 + a*7 + bb];
                    float w1 = filt_s[1*49 + a*7 + bb];
                    y4[0].x = fmaf(w0, xv.x, y4[0].x); y4[0].y = fmaf(w0, xv.y, y4[0].y);
                    y4[0].z = fmaf(w0, xv.z, y4[0].z); y4[0].w = fmaf(w0, xv.w, y4[0].w);
                    y4[1].x = fmaf(w1, xv.x, y4[1].x); y4[1].y = fmaf(w1, xv.y, y4[1].y);
                    y4[1].z = fmaf(w1, xv.z, y4[1].z); y4[1].w = fmaf(w1, xv.w, y4[1].w);
                }
            }
        }
        float4 m5 = make_float4(-INFINITY,-INFINITY,-INFINITY,-INFINITY);
        #pragma unroll
        for (int dy = -2; dy <= 2; dy++) {
            #pragma unroll
            for (int dx2 = -2; dx2 <= 2; dx2++) {
                if ((unsigned)(gy+dy) < 256u && (unsigned)(gx+dx2) < 256u)
                    m5 = f4max(m5, *(const float4*)&xs[((py+3+dy)*14 + (px1+3+dx2))*20 + q4]);
            }
        }
        float4 xc = *(const float4*)&xs[((py+3)*14 + (px1+3))*20 + q4];

        #define SPLIT4(arridx, v) { \
            unsigned short h0 = bf16_rne((v).x), h1 = bf16_rne((v).y); \
            unsigned short h2 = bf16_rne((v).z), h3 = bf16_rne((v).w); \
            unsigned short l0 = bf16_rne((v).x - bf16f(h0)); \
            unsigned short l1 = bf16_rne((v).y - bf16f(h1)); \
            unsigned short l2 = bf16_rne((v).z - bf16f(h2)); \
            unsigned short l3 = bf16_rne((v).w - bf16f(h3)); \
            *(ushort4*)&perc_hi[arridx] = make_ushort4(h0,h1,h2,h3); \
            *(ushort4*)&perc_lo[arridx] = make_ushort4(l0,l1,l2,l3); }

        const int prow = p * 136;
        SPLIT4(prow +       q4, xc);
        SPLIT4(prow + 16  + q4, y4[0]);
        SPLIT4(prow + 32  + q4, y4[1]);
        SPLIT4(prow + 48  + q4, y4[2]);
        SPLIT4(prow + 64  + q4, y4[3]);
        SPLIT4(prow + 80  + q4, y4[4]);
        SPLIT4(prow + 96  + q4, y4[5]);
        SPLIT4(prow + 112 + q4, m5);
        #undef SPLIT4

        if (q == 0) {
            float pre = -INFINITY;
            #pragma unroll
            for (int dy = -1; dy <= 1; dy++) {
                #pragma unroll
                for (int dx2 = -1; dx2 <= 1; dx2++) {
                    if ((unsigned)(gy+dy) < 256u && (unsigned)(gx+dx2) < 256u)
                        pre = fmaxf(pre, xs[((py+3+dy)*14 + (px1+3+dx2))*20 + 3]);
                }
            }
            prelife_out[(b << 16) + (gy << 8) + gx] = (pre > 0.1f) ? 1 : 0;
        }
    }
    __syncthreads();   // xs reads done; perc published. xs region -> w0.

    // ---- phase 2: GEMM1 + GEMM2 both MFMA ----
    const int lane = t & 63;
    const int wid  = t >> 6;        // m-tile (16 px)
    const int l15  = lane & 15;
    const int l4   = lane >> 4;
    const int aoff  = (wid*16 + l15)*136 + 8*l4;  // GEMM1 A base (+32*ks)
    const int boff0 = (l15)*136 + 8*l4;           // GEMM1 B, n-tile 0
    const int boff1 = (16 + l15)*136 + 8*l4;      // GEMM1 B, n-tile 1
    const int hwr   = (wid*16 + 4*l4)*36 + l15;   // hbuf write base (+r*36)
    const int hrd   = (wid*16 + l15)*36 + 8*l4;   // hbuf A-frag base
    const int w1off = l15*256 + 8*l4;             // W1T2 frag base (+jc*32)

    // hoist GEMM1 A-frags (loop-invariant)
    short8 ah0 = *(const short8*)&perc_hi[aoff +  0];
    short8 ah1 = *(const short8*)&perc_hi[aoff + 32];
    short8 ah2 = *(const short8*)&perc_hi[aoff + 64];
    short8 ah3 = *(const short8*)&perc_hi[aoff + 96];
    short8 al0 = *(const short8*)&perc_lo[aoff +  0];
    short8 al1 = *(const short8*)&perc_lo[aoff + 32];
    short8 al2 = *(const short8*)&perc_lo[aoff + 64];
    short8 al3 = *(const short8*)&perc_lo[aoff + 96];

    f32x4 dacc = {0.f, 0.f, 0.f, 0.f};   // dx accumulator (C: col=ch, row=px)

    // prologue: write chunk 0 -> A buf; prefetch chunk 1
    *(uint4*)&w0hA[swds]     = sh0;
    *(uint4*)&w0hA[swds + 8] = sh1;
    *(uint4*)&w0lA[swds]     = sl0;
    *(uint4*)&w0lA[swds + 8] = sl1;
    sh0 = *(const uint4*)&W0hiT[sgbase + 4096];
    sh1 = *(const uint4*)&W0hiT[sgbase + 4096 + 8];
    sl0 = *(const uint4*)&W0loT[sgbase + 4096];
    sl1 = *(const uint4*)&W0loT[sgbase + 4096 + 8];
    __syncthreads();   // w0(0) visible

    #pragma unroll 1
    for (int jc = 0; jc < 8; jc++) {
        const unsigned short* wrdh = (jc & 1) ? w0hB : w0hA;
        const unsigned short* wrdl = (jc & 1) ? w0lB : w0lA;
        unsigned short*       wwrh = (jc & 1) ? w0hA : w0hB;
        unsigned short*       wwrl = (jc & 1) ? w0lA : w0lB;

        f32x4 acc0 = {0.f, 0.f, 0.f, 0.f};
        f32x4 acc1 = {0.f, 0.f, 0.f, 0.f};

        #define KSTEP(accv, boff, AH, AL, ks) { \
            short8 bh = *(const short8*)&wrdh[(boff) + (ks)*32]; \
            short8 bl = *(const short8*)&wrdl[(boff) + (ks)*32]; \
            accv = __builtin_amdgcn_mfma_f32_16x16x32_bf16(AL, bh, accv, 0, 0, 0); \
            accv = __builtin_amdgcn_mfma_f32_16x16x32_bf16(AH, bl, accv, 0, 0, 0); \
            accv = __builtin_amdgcn_mfma_f32_16x16x32_bf16(AH, bh, accv, 0, 0, 0); }

        KSTEP(acc0, boff0, ah0, al0, 0)
        KSTEP(acc0, boff0, ah1, al1, 1)
        KSTEP(acc0, boff0, ah2, al2, 2)
        KSTEP(acc0, boff0, ah3, al3, 3)
        KSTEP(acc1, boff1, ah0, al0, 0)
        KSTEP(acc1, boff1, ah1, al1, 1)
        KSTEP(acc1, boff1, ah2, al2, 2)
        KSTEP(acc1, boff1, ah3, al3, 3)
        #undef KSTEP

        // bias+relu, split h -> hbuf (WAVE-LOCAL: no barrier needed)
        {
            float bias0 = b0[jc*32 + l15];
            float bias1 = b0[jc*32 + 16 + l15];
            #pragma unroll
            for (int r = 0; r < 4; r++) {
                float h0 = fmaxf(acc0[r] + bias0, 0.f);
                float h1 = fmaxf(acc1[r] + bias1, 0.f);
                unsigned short hh0 = bf16_rne(h0);
                unsigned short hl0 = bf16_rne(h0 - bf16f(hh0));
                unsigned short hh1 = bf16_rne(h1);
                unsigned short hl1 = bf16_rne(h1 - bf16f(hh1));
                hbuf_hi[hwr + r*36]      = hh0;
                hbuf_lo[hwr + r*36]      = hl0;
                hbuf_hi[hwr + r*36 + 16] = hh1;
                hbuf_lo[hwr + r*36 + 16] = hl1;
            }
        }

        // GEMM2: dacc += h(px x 32j) * W1T2(32j x 16ch), 3 MFMAs
        {
            short8 hhf = *(const short8*)&hbuf_hi[hrd];
            short8 hlf = *(const short8*)&hbuf_lo[hrd];
            short8 w1h = *(const short8*)&W1hiT2[w1off + jc*32];
            short8 w1l = *(const short8*)&W1loT2[w1off + jc*32];
            dacc = __builtin_amdgcn_mfma_f32_16x16x32_bf16(hlf, w1h, dacc, 0, 0, 0);
            dacc = __builtin_amdgcn_mfma_f32_16x16x32_bf16(hhf, w1l, dacc, 0, 0, 0);
            dacc = __builtin_amdgcn_mfma_f32_16x16x32_bf16(hhf, w1h, dacc, 0, 0, 0);
        }

        // stage chunk jc+1 into other buffer (holds consumed chunk jc-1)
        if (jc < 7) {
            *(uint4*)&wwrh[swds]     = sh0;
            *(uint4*)&wwrh[swds + 8] = sh1;
            *(uint4*)&wwrl[swds]     = sl0;
            *(uint4*)&wwrl[swds + 8] = sl1;
            if (jc < 6) {
                const int nb = sgbase + (jc + 2) * 4096;
                sh0 = *(const uint4*)&W0hiT[nb];
                sh1 = *(const uint4*)&W0hiT[nb + 8];
                sl0 = *(const uint4*)&W0loT[nb];
                sl1 = *(const uint4*)&W0loT[nb + 8];
            }
            __syncthreads();   // one barrier per chunk
        }
    }

    // ---- epilogue: lane = (ch=l15, px=16*wid+4*l4+r) ----
    const int pxb = wid*16 + 4*l4;
    #pragma unroll
    for (int r = 0; r < 4; r++) {
        const int px   = pxb + r;
        const int pix2 = (b << 16) + ((ty0 + (px >> 3)) << 8) + (tx0 + (px & 7));
        float fire = (stoch_s[pix2] > 0.5f) ? 1.f : 0.f;
        float xc = bf16f(perc_hi[px*136 + l15]) + bf16f(perc_lo[px*136 + l15]);
        xmid[((size_t)pix2 << 4) + l15] = fmaf(fire, dacc[r], xc);
    }
}

// Final life masking (after step 16): alpha read from xbuf channel 3.
__global__ void step_mask(float* __restrict__ xbuf,
                          const unsigned char* __restrict__ prelife,
                          const float* __restrict__ valid) {
    int pix = blockIdx.x * 256 + threadIdx.x;
    int b = pix >> 16;
    int y = (pix >> 8) & 255;
    int x = pix & 255;
    float m = -INFINITY;
    #pragma unroll
    for (int dy = -1; dy <= 1; dy++) {
        #pragma unroll
        for (int dxo = -1; dxo <= 1; dxo++) {
            int yy = y + dy, xx = x + dxo;
            if ((unsigned)yy < 256u && (unsigned)xx < 256u)
                m = fmaxf(m, xbuf[((size_t)((b << 16) + (yy << 8) + xx) << 4) + 3]);
        }
    }
    float s = (prelife[pix] != 0 && m > 0.1f) ? valid[pix] : 0.f;
    float4* xp = (float4*)&xbuf[(size_t)pix << 4];
    #pragma unroll
    for (int i = 0; i < 4; i++) {
        float4 v = xp[i];
        v.x *= s; v.y *= s; v.z *= s; v.w *= s;
        xp[i] = v;
    }
}

extern "C" void kernel_launch(void* const* d_in, const int* in_sizes, int n_in,
                              void* d_out, int out_size, void* d_ws, size_t ws_size,
                              hipStream_t stream) {
    const float* x0    = (const float*)d_in[0];
    const float* valid = (const float*)d_in[1];
    const float* stoch = (const float*)d_in[2];
    const float* W0    = (const float*)d_in[3];
    const float* b0    = (const float*)d_in[4];
    const float* W1    = (const float*)d_in[5];

    float* ws   = (float*)d_ws;
    float* xA   = ws;                                    // [0, 8388608)
    unsigned char* plA = (unsigned char*)(ws + 8388608); // 512KB
    unsigned char* plB = plA + 524288;                   // 512KB
    float* filt = ws + 8650752;                          // 320 fl
    unsigned short* W0hiT  = (unsigned short*)(ws + 8651072);  // 32768 us
    unsigned short* W0loT  = (unsigned short*)(ws + 8667456);  // 32768 us
    unsigned short* W1hiT2 = (unsigned short*)(ws + 8683840);  // 4096 us
    unsigned short* W1loT2 = (unsigned short*)(ws + 8685888);  // 4096 us
    float* out  = (float*)d_out;

    init_kernel<<<128, 256, 0, stream>>>(W0, W1, filt, W0hiT, W0loT,
                                         W1hiT2, W1loT2);

    const float* src = x0;
    for (int k = 1; k <= 16; k++) {
        float* dst = (k & 1) ? xA : out;          // step 16 lands in d_out
        unsigned char* wr = (k & 1) ? plB : plA;
        unsigned char* rd = (k & 1) ? plA : plB;
        step_main<<<dim3(32,32,8), 256, 0, stream>>>(
            src, dst, rd, wr, filt, W0hiT, W0loT, W1hiT2, W1loT2, b0,
            stoch + (size_t)(k-1)*NPIX, valid, (k > 1) ? 1 : 0);
        src = dst;
    }
    step_mask<<<NPIX/256, 256, 0, stream>>>(out, plA, valid);
}